// Round 4
// baseline (207.423 us; speedup 1.0000x reference)
//
#include <hip/hip_runtime.h>
#include <hip/hip_bf16.h>

#define NH 8
#define DH 64
#define SL 512

typedef __bf16 bf16x8 __attribute__((ext_vector_type(8)));
typedef float f32x16 __attribute__((ext_vector_type(16)));
typedef float f32x4 __attribute__((ext_vector_type(4)));
typedef unsigned int u32;

#define MFMA(a, b, c) __builtin_amdgcn_mfma_f32_32x32x16_bf16(a, b, c, 0, 0, 0)
#define ZERO16 {0.f,0.f,0.f,0.f,0.f,0.f,0.f,0.f,0.f,0.f,0.f,0.f,0.f,0.f,0.f,0.f}

__device__ __forceinline__ unsigned short f2bf(float x) {   // RN-even fp32->bf16 (bit-exact w/ r3)
    union { float f; u32 u; } v; v.f = x;
    return (unsigned short)((v.u + 0x7fffu + ((v.u >> 16) & 1u)) >> 16);
}

// split 8 fp32 (two f32x4) into hi/lo bf16x8 via compiler-lowered cvt (v_cvt_pk_bf16_f32 pairs)
__device__ __forceinline__ void split8(const f32x4 a, const f32x4 b, bf16x8& h8, bf16x8& l8) {
    union { __hip_bfloat16 s[8]; bf16x8 v; } uh, ul;
#pragma unroll
    for (int i = 0; i < 4; ++i) {
        __hip_bfloat16 h0 = __float2bfloat16(a[i]);
        __hip_bfloat16 h1 = __float2bfloat16(b[i]);
        uh.s[i] = h0; uh.s[4 + i] = h1;
        ul.s[i]     = __float2bfloat16(a[i] - __bfloat162float(h0));
        ul.s[4 + i] = __float2bfloat16(b[i] - __bfloat162float(h1));
    }
    h8 = uh.v; l8 = ul.v;
}
// hi-only RN convert (E path — precision-critical, keep round-3 bit-exact RN)
__device__ __forceinline__ void cvt8(const f32x4 a, const f32x4 b, bf16x8& h8) {
    union { unsigned short s[8]; bf16x8 v; } uh;
#pragma unroll
    for (int i = 0; i < 4; ++i) { uh.s[i] = f2bf(a[i]); uh.s[4 + i] = f2bf(b[i]); }
    h8 = uh.v;
}

// ---------- dtype-detect: is the input buffer bf16 or fp32? ----------
__global__ void detect_dtype_kernel(const unsigned short* __restrict__ q, int* __restrict__ flag) {
    int t = threadIdx.x;
    unsigned int u = (unsigned int)q[t];
    float f = __uint_as_float(u << 16);
    bool big = !(fabsf(f) <= 1e4f);   // true for huge OR NaN
    unsigned long long vote = __ballot(big);
    __shared__ int any;
    if (t == 0) any = 0;
    __syncthreads();
    if (vote != 0ull && (t & 63) == 0) atomicOr(&any, 1);
    __syncthreads();
    if (t == 0) *flag = any;          // 1 => fp32 data, 0 => bf16 data
}

// ---------- load/store helpers (fallback path) ----------
__device__ __forceinline__ float ldv(const __hip_bfloat16* p) { return __bfloat162float(*p); }
__device__ __forceinline__ float ldv(const float* p) { return *p; }
__device__ __forceinline__ void stv(__hip_bfloat16* p, float v) { *p = __float2bfloat16(v); }
__device__ __forceinline__ void stv(float* p, float v) { *p = v; }

// ---------- fused flash attention w/ relative logits, FP32 via split-bf16 MFMA (MODE 1) ----------
// 1024 blocks: one per (bh, 32-row l-tile). 4 waves = 4 m-quarters (128 m each), 4-way flash
// merge at the end. ZERO in-loop barriers: Q/K fragments gathered direct from global (L2-hot)
// and split hi/lo in registers; E rows register-reused across steps (ec -> ea).
// S^T = Kh*Qh + Kh*Ql + Kl*Qh; rel = Eh*Qh sheared via per-wave XOR-swizzled LDS bounce;
// O^T = (Vh+Vl)*P^T with P bf16 (sum of rounded P for consistent normalization).
__global__ __launch_bounds__(256, 3) void attn_flash_f32(
    const float* __restrict__ qkv,      // [bh][3*64][512]
    const float* __restrict__ k_emb,    // [H][1023][64]
    float* __restrict__ out,            // [bh][512][64] raw
    const int* __restrict__ flag)
{
    if (*flag != 1) return;
    const int bid = blockIdx.x;
    // XCD swizzle: XCD c gets bh in [8c,8c+8) entirely (K/V/k_emb L2-resident per XCD)
    const int swz = (bid & 7) * 128 + (bid >> 3);
    const int bh = swz >> 4, lt = swz & 15;
    const int h  = bh & (NH - 1);
    const int t = threadIdx.x;
    const int wid = t >> 6, lane = t & 63;
    const int lo = lane & 31, hi = lane >> 5;
    const int mq = wid;                 // m-quarter of this wave
    const int l0 = lt * 32;

    __shared__ float srect[4][2048];    // per-wave rel rect [l'][j] (XOR-swizzled); o-publish at merge
    __shared__ float sstat[4][2][32];   // [wave][mx|sum][l']

    const float* qbase = qkv + (size_t)bh * (3 * DH * SL);
    const float* kglob = qbase + DH * SL;
    const float* vflat = qbase + (size_t)2 * DH * SL;
    const float* ebase = k_emb + (size_t)h * (2 * SL - 1) * DH;

    // ---- Q fragments: direct strided gather (coalesced across lanes), reg split ----
    bf16x8 qfh[4], qfl[4];
#pragma unroll
    for (int ds = 0; ds < 4; ++ds) {
        const float* qp = qbase + (size_t)(16 * ds + 8 * hi) * SL + (l0 + lo);
        f32x4 xa, xb;
#pragma unroll
        for (int i = 0; i < 4; ++i) { xa[i] = qp[(size_t)i * SL]; xb[i] = qp[(size_t)(4 + i) * SL]; }
        split8(xa, xb, qfh[ds], qfl[ds]);
    }

    // ---- initial E fragments (rows rb0+lo), hi-only ----
    const int rb0 = mq * 128 - l0 + 480;          // >= 0 always
    bf16x8 eah[4];
    {
        const float* e0p = ebase + (size_t)(rb0 + lo) * DH;
#pragma unroll
        for (int ds = 0; ds < 4; ++ds) {
            const int off = 16 * ds + 8 * hi;
            cvt8(*(const f32x4*)(e0p + off), *(const f32x4*)(e0p + off + 4), eah[ds]);
        }
    }

    float* rect = srect[wid];
    float* rrow = rect + lo * 64;
    const int sw = (lo & 7) << 2;       // XOR col-swizzle: conflict-free rect access

    f32x16 o0 = ZERO16, o1 = ZERO16;    // O^T accum: d 0-31 / 32-63, col l' = lo
    float mx = -1e30f, sum = 0.f;

    for (int step = 0; step < 4; ++step) {
        const int m0 = mq * 128 + step * 32;
        const int rb = rb0 + step * 32;

        // ---- K fragments: direct strided gather + reg hi/lo split ----
        bf16x8 kh[4], kl[4];
#pragma unroll
        for (int ds = 0; ds < 4; ++ds) {
            const float* kp = kglob + (size_t)(16 * ds + 8 * hi) * SL + (m0 + lo);
            f32x4 xa, xb;
#pragma unroll
            for (int i = 0; i < 4; ++i) { xa[i] = kp[(size_t)i * SL]; xb[i] = kp[(size_t)(4 + i) * SL]; }
            split8(xa, xb, kh[ds], kl[ds]);
        }
        // ---- E lower half (rows rb+32+lo, clamp only hits unused j=63 at last step) ----
        bf16x8 ech[4];
        {
            int r1 = rb + 32 + lo; if (r1 > 1022) r1 = 1022;
            const float* e1p = ebase + (size_t)r1 * DH;
#pragma unroll
            for (int ds = 0; ds < 4; ++ds) {
                const int off = 16 * ds + 8 * hi;
                cvt8(*(const f32x4*)(e1p + off), *(const f32x4*)(e1p + off + 4), ech[ds]);
            }
        }
        // ---- V fragments hi/lo (native [d][m] fp32 rows) ----
        const float* v0p = vflat + (size_t)lo * SL + m0 + 8 * hi;
        const float* v1p = vflat + (size_t)(32 + lo) * SL + m0 + 8 * hi;
        bf16x8 v00h, v00l, v01h, v01l, v10h, v10l, v11h, v11l;
        split8(*(const f32x4*)v0p,        *(const f32x4*)(v0p + 4),  v00h, v00l);
        split8(*(const f32x4*)(v0p + 16), *(const f32x4*)(v0p + 20), v01h, v01l);
        split8(*(const f32x4*)v1p,        *(const f32x4*)(v1p + 4),  v10h, v10l);
        split8(*(const f32x4*)(v1p + 16), *(const f32x4*)(v1p + 20), v11h, v11l);

        // ---- MFMA block: S^T (3-term split) + rel rect ----
        f32x16 ra = ZERO16, rc = ZERO16, sacc = ZERO16;
        __builtin_amdgcn_s_setprio(1);
#pragma unroll
        for (int ds = 0; ds < 4; ++ds) {
            sacc = MFMA(kh[ds], qfh[ds], sacc);
            sacc = MFMA(kh[ds], qfl[ds], sacc);
            sacc = MFMA(kl[ds], qfh[ds], sacc);
            ra   = MFMA(eah[ds], qfh[ds], ra);   // rel rows j = 0..31
            rc   = MFMA(ech[ds], qfh[ds], rc);   // rel rows j = 32..63
        }
        __builtin_amdgcn_s_setprio(0);

        // rect -> LDS [l'][j^sw] (8 x b128, conflict-free), sheared gather back (own row)
#pragma unroll
        for (int g = 0; g < 4; ++g) {
            const int j0 = 8 * g + 4 * hi;
            f32x4 w0 = { ra[4 * g], ra[4 * g + 1], ra[4 * g + 2], ra[4 * g + 3] };
            f32x4 w1 = { rc[4 * g], rc[4 * g + 1], rc[4 * g + 2], rc[4 * g + 3] };
            *(f32x4*)(rrow + (j0 ^ sw))        = w0;
            *(f32x4*)(rrow + ((j0 + 32) ^ sw)) = w1;
        }
        float s[16];
#pragma unroll
        for (int r = 0; r < 16; ++r) {
            const int mp = (r & 3) + 8 * (r >> 2) + 4 * hi;   // m' of this reg
            s[r] = sacc[r] + rrow[(mp + 31 - lo) ^ sw];       // + rel^T[j=m'+31-l'][l']
        }

        // ---- online softmax (per-lane col l'; hi-pair merged via shfl_xor 32) ----
        float tmx = s[0];
#pragma unroll
        for (int r = 1; r < 16; ++r) tmx = fmaxf(tmx, s[r]);
        tmx = fmaxf(tmx, __shfl_xor(tmx, 32, 64));
        const float nmx = fmaxf(mx, tmx);
        if (__any(nmx > mx)) {
            const float sc = __expf(mx - nmx);
#pragma unroll
            for (int r = 0; r < 16; ++r) { o0[r] *= sc; o1[r] *= sc; }
            sum *= sc;
            mx = nmx;
        }
        u32 pk[8], xk[8];
        float ps = 0.f;
#pragma unroll
        for (int q2 = 0; q2 < 8; ++q2) {
            union { __hip_bfloat162 b; u32 u; } cv;
            cv.b = __float22bfloat162_rn(make_float2(__expf(s[2 * q2] - mx),
                                                     __expf(s[2 * q2 + 1] - mx)));
            pk[q2] = cv.u;
            float2 g2 = __bfloat1622float2(cv.b);   // sum the *rounded* P for consistency
            ps += g2.x + g2.y;
        }
        sum += ps;
#pragma unroll
        for (int q2 = 0; q2 < 8; ++q2) xk[q2] = (u32)__shfl_xor((int)pk[q2], 32, 64);

        // P^T B-fragments (k = m within 16-slice; swap middle quads with hi-partner)
        union { u32 u[4]; bf16x8 v; } pf0, pf1;
        if (hi == 0) {
            pf0.u[0] = pk[0]; pf0.u[1] = pk[1]; pf0.u[2] = xk[0]; pf0.u[3] = xk[1];
            pf1.u[0] = pk[4]; pf1.u[1] = pk[5]; pf1.u[2] = xk[4]; pf1.u[3] = xk[5];
        } else {
            pf0.u[0] = xk[2]; pf0.u[1] = xk[3]; pf0.u[2] = pk[2]; pf0.u[3] = pk[3];
            pf1.u[0] = xk[6]; pf1.u[1] = xk[7]; pf1.u[2] = pk[6]; pf1.u[3] = pk[7];
        }
        __builtin_amdgcn_s_setprio(1);
        o0 = MFMA(v00h, pf0.v, o0);
        o0 = MFMA(v00l, pf0.v, o0);
        o0 = MFMA(v01h, pf1.v, o0);
        o0 = MFMA(v01l, pf1.v, o0);
        o1 = MFMA(v10h, pf0.v, o1);
        o1 = MFMA(v10l, pf0.v, o1);
        o1 = MFMA(v11h, pf1.v, o1);
        o1 = MFMA(v11l, pf1.v, o1);
        __builtin_amdgcn_s_setprio(0);

        // ---- E register reuse: this step's lower rows are next step's upper rows ----
#pragma unroll
        for (int ds = 0; ds < 4; ++ds) eah[ds] = ech[ds];
    }

    // merge hi-pair partial sums (mx already identical across the pair)
    sum += __shfl_xor(sum, 32, 64);

    // ---- 4-way flash merge: waves 1-3 publish, wave 0 combines & stores ----
    if (wid > 0) {
        if (hi == 0) { sstat[wid][0][lo] = mx; sstat[wid][1][lo] = sum; }
        float* ob = rect;   // reuse own rect region as [d][l'] (stride 32, conflict-free)
#pragma unroll
        for (int r = 0; r < 16; ++r) {
            const int d0 = (r & 3) + 8 * (r >> 2) + 4 * hi;
            ob[d0 * 32 + lo]        = o0[r];
            ob[(32 + d0) * 32 + lo] = o1[r];
        }
    }
    __syncthreads();
    if (wid == 0) {
        const float m1 = sstat[1][0][lo], s1 = sstat[1][1][lo];
        const float m2 = sstat[2][0][lo], s2 = sstat[2][1][lo];
        const float m3 = sstat[3][0][lo], s3 = sstat[3][1][lo];
        const float nm = fmaxf(fmaxf(mx, m1), fmaxf(m2, m3));
        const float a0 = __expf(mx - nm);
        const float a1 = __expf(m1 - nm);
        const float a2 = __expf(m2 - nm);
        const float a3 = __expf(m3 - nm);
        const float inv = 1.f / (a0 * sum + a1 * s1 + a2 * s2 + a3 * s3);
        const float* ob1 = srect[1];
        const float* ob2 = srect[2];
        const float* ob3 = srect[3];
        float* orow = out + ((size_t)bh * SL + l0 + lo) * DH;
#pragma unroll
        for (int r = 0; r < 16; r += 2) {
            const int d0 = (r & 3) + 8 * (r >> 2) + 4 * hi;   // even; (r,r+1)->(d0,d0+1)
            float2 w0 = make_float2(
                (a0 * o0[r]     + a1 * ob1[d0 * 32 + lo] + a2 * ob2[d0 * 32 + lo] + a3 * ob3[d0 * 32 + lo]) * inv,
                (a0 * o0[r + 1] + a1 * ob1[(d0 + 1) * 32 + lo] + a2 * ob2[(d0 + 1) * 32 + lo] + a3 * ob3[(d0 + 1) * 32 + lo]) * inv);
            *(float2*)(orow + d0) = w0;
            float2 w1 = make_float2(
                (a0 * o1[r]     + a1 * ob1[(32 + d0) * 32 + lo] + a2 * ob2[(32 + d0) * 32 + lo] + a3 * ob3[(32 + d0) * 32 + lo]) * inv,
                (a0 * o1[r + 1] + a1 * ob1[(32 + d0 + 1) * 32 + lo] + a2 * ob2[(32 + d0 + 1) * 32 + lo] + a3 * ob3[(32 + d0 + 1) * 32 + lo]) * inv);
            *(float2*)(orow + 32 + d0) = w1;
        }
    }
}

// ---------- scalar fallback (bf16 MODE 0) — inert when data is fp32 ----------
template <typename T, int MODE>
__global__ __launch_bounds__(256) void attn_rel_kernel(
    const T* __restrict__ qkv, const T* __restrict__ k_emb,
    T* __restrict__ out, const int* __restrict__ flag)
{
    if (*flag != MODE) return;
    const int t = threadIdx.x;
    __shared__ float s_q[DH];
    __shared__ float s_w[SL];
    __shared__ float s_red[24];
    __shared__ float s_part[256];

    for (int it = 0; it < 16; ++it) {
        const int bid = blockIdx.x * 16 + it;
        const int l   = bid & (SL - 1);
        const int bh  = bid >> 9;
        const int h   = bh & (NH - 1);
        const long base = (long)bh * (3 * DH) * SL;

        __syncthreads();
        if (t < DH) s_q[t] = ldv(&qkv[base + (long)t * SL + l]);
        __syncthreads();

        const T* kp = qkv + base + (long)DH * SL;
        const T* ke = k_emb + (long)h * (2 * SL - 1) * DH;
        float lg[2];
#pragma unroll
        for (int i = 0; i < 2; ++i) {
            const int m = t + i * 256;
            float acc = 0.f;
#pragma unroll 8
            for (int d = 0; d < DH; ++d)
                acc += s_q[d] * ldv(&kp[(long)d * SL + m]);
            const int r = m - l + (SL - 1);
            const T* kr = ke + (long)r * DH;
            float acc2 = 0.f;
#pragma unroll 8
            for (int d = 0; d < DH; ++d)
                acc2 += s_q[d] * ldv(&kr[d]);
            lg[i] = acc + acc2;
        }

        float mxv = fmaxf(lg[0], lg[1]);
        for (int off = 32; off > 0; off >>= 1)
            mxv = fmaxf(mxv, __shfl_down(mxv, off, 64));
        if ((t & 63) == 0) s_red[t >> 6] = mxv;
        __syncthreads();
        if (t == 0)
            s_red[8] = fmaxf(fmaxf(s_red[0], s_red[1]), fmaxf(s_red[2], s_red[3]));
        __syncthreads();
        mxv = s_red[8];

        const float e0 = expf(lg[0] - mxv);
        const float e1 = expf(lg[1] - mxv);
        s_w[t] = e0;
        s_w[t + 256] = e1;
        float sm = e0 + e1;
        for (int off = 32; off > 0; off >>= 1)
            sm += __shfl_down(sm, off, 64);
        if ((t & 63) == 0) s_red[16 + (t >> 6)] = sm;
        __syncthreads();
        const float inv = 1.0f / (s_red[16] + s_red[17] + s_red[18] + s_red[19]);

        const T* vp = qkv + base + (long)(2 * DH) * SL;
        const int g  = t >> 6;
        const int dd = t & 63;
        const T* vrow = vp + (long)dd * SL + g * 128;
        const float* wrow = s_w + g * 128;
        float acc = 0.f;
#pragma unroll 8
        for (int m = 0; m < 128; ++m)
            acc += wrow[m] * ldv(&vrow[m]);
        s_part[t] = acc;
        __syncthreads();
        if (t < 64) {
            float o = (s_part[t] + s_part[t + 64] + s_part[t + 128] + s_part[t + 192]) * inv;
            stv(&out[((long)bh * SL + l) * DH + t], o);
        }
    }
}

extern "C" void kernel_launch(void* const* d_in, const int* in_sizes, int n_in,
                              void* d_out, int out_size, void* d_ws, size_t ws_size,
                              hipStream_t stream) {
    (void)in_sizes; (void)n_in; (void)out_size; (void)ws_size;
    int* flag = (int*)d_ws;

    detect_dtype_kernel<<<1, 256, 0, stream>>>((const unsigned short*)d_in[0], flag);

    // fp32 flash path (MODE 1) — the real path for this harness
    attn_flash_f32<<<1024, 256, 0, stream>>>(
        (const float*)d_in[0], (const float*)d_in[1], (float*)d_out, flag);

    // bf16 scalar fallback (MODE 0) — self-disables via flag when data is fp32
    attn_rel_kernel<__hip_bfloat16, 0><<<2048, 256, 0, stream>>>(
        (const __hip_bfloat16*)d_in[0], (const __hip_bfloat16*)d_in[1],
        (__hip_bfloat16*)d_out, flag);
}

// Round 5
// 113.569 us; speedup vs baseline: 1.8264x; 1.8264x over previous
//
#include <hip/hip_runtime.h>
#include <hip/hip_bf16.h>

#define NH 8
#define DH 64
#define SL 512

typedef __bf16 bf16x8 __attribute__((ext_vector_type(8)));
typedef float f32x16 __attribute__((ext_vector_type(16)));
typedef float f32x4 __attribute__((ext_vector_type(4)));
typedef unsigned int u32;

#define MFMA(a, b, c) __builtin_amdgcn_mfma_f32_32x32x16_bf16(a, b, c, 0, 0, 0)
#define ZERO16 {0.f,0.f,0.f,0.f,0.f,0.f,0.f,0.f,0.f,0.f,0.f,0.f,0.f,0.f,0.f,0.f}

__device__ __forceinline__ unsigned short f2bf(float x) {   // RN-even fp32->bf16
    union { float f; u32 u; } v; v.f = x;
    return (unsigned short)((v.u + 0x7fffu + ((v.u >> 16) & 1u)) >> 16);
}

// split 8 fp32 (two f32x4) into hi/lo bf16x8 (compiler lowers to v_cvt pairs)
__device__ __forceinline__ void split8(const f32x4 a, const f32x4 b, bf16x8& h8, bf16x8& l8) {
    union { __hip_bfloat16 s[8]; bf16x8 v; } uh, ul;
#pragma unroll
    for (int i = 0; i < 4; ++i) {
        __hip_bfloat16 h0 = __float2bfloat16(a[i]);
        __hip_bfloat16 h1 = __float2bfloat16(b[i]);
        uh.s[i] = h0; uh.s[4 + i] = h1;
        ul.s[i]     = __float2bfloat16(a[i] - __bfloat162float(h0));
        ul.s[4 + i] = __float2bfloat16(b[i] - __bfloat162float(h1));
    }
    h8 = uh.v; l8 = ul.v;
}
// hi-only RN convert (E path)
__device__ __forceinline__ void cvt8(const f32x4 a, const f32x4 b, bf16x8& h8) {
    union { unsigned short s[8]; bf16x8 v; } uh;
#pragma unroll
    for (int i = 0; i < 4; ++i) { uh.s[i] = f2bf(a[i]); uh.s[4 + i] = f2bf(b[i]); }
    h8 = uh.v;
}

__device__ __forceinline__ float ldv(const __hip_bfloat16* p) { return __bfloat162float(*p); }
__device__ __forceinline__ void stv(__hip_bfloat16* p, float v) { *p = __float2bfloat16(v); }

// ---------- single fused kernel: self-detect dtype, flash-MFMA fp32 path, scalar bf16 fallback ----------
// 1024 blocks x 256. Flash path: one block per (bh, 32-row l-tile); 4 waves = 4 m-quarters,
// ZERO in-loop barriers (Q/K/E/V gathered direct from global, hi/lo split in registers);
// 4-way flash merge at the end (one barrier). Head-major XCD swizzle: h = bid&7 so each XCD's
// L2 holds one k_emb head (256KB) + 8 bh QKV panels (~3MB) < 4MB.
// S^T = Kh*Qh + Kh*Ql + Kl*Qh; rel = Eh*Qh sheared via per-wave XOR-swizzled LDS bounce;
// O^T = (Vh+Vl)*P^T, P bf16 (sum of rounded P for consistent normalization).
__global__ __launch_bounds__(256, 2) void attn_fused(
    const void* __restrict__ qkv_v,     // [bh][3*64][512] fp32 or bf16
    const void* __restrict__ k_emb_v,   // [H][1023][64]
    void* __restrict__ out_v)           // [bh][512][64] raw
{
    const int t = threadIdx.x;
    const int bid = blockIdx.x;

    // ---- in-block dtype detect (fp32 reinterpreted as bf16 has |x|>1e4 or NaN halves) ----
    __shared__ int s_flag;
    {
        unsigned int u = (unsigned int)((const unsigned short*)qkv_v)[t];
        float f = __uint_as_float(u << 16);
        bool big = !(fabsf(f) <= 1e4f);
        unsigned long long vote = __ballot(big);
        if (t == 0) s_flag = 0;
        __syncthreads();
        if (vote != 0ull && (t & 63) == 0) atomicOr(&s_flag, 1);
        __syncthreads();
    }
    const bool is_f32 = (s_flag != 0);

    __shared__ float srect[4][2048];    // per-wave rel rect [l'][j] (XOR-swizzled); o-publish at merge
    __shared__ float sstat[4][2][32];   // [wave][mx|sum][l']
    __shared__ float s_w[SL];           // fallback-path scratch
    __shared__ float s_red[24];
    __shared__ float s_part[256];
    __shared__ float s_q[DH];

    if (is_f32) {
        // ================= flash path (fp32 data) =================
        const float* qkv   = (const float*)qkv_v;
        const float* k_emb = (const float*)k_emb_v;
        float* out         = (float*)out_v;

        // head-major XCD swizzle: XCD c <- all blocks of head h=c
        const int h    = bid & 7;
        const int rest = bid >> 3;          // 0..127
        const int b    = rest & 7;
        const int lt   = rest >> 3;         // 0..15
        const int bh   = b * NH + h;
        const int wid = t >> 6, lane = t & 63;
        const int lo = lane & 31, hi = lane >> 5;
        const int mq = wid;                 // m-quarter of this wave
        const int l0 = lt * 32;

        const float* qbase = qkv + (size_t)bh * (3 * DH * SL);
        const float* kglob = qbase + DH * SL;
        const float* vflat = qbase + (size_t)2 * DH * SL;
        const float* ebase = k_emb + (size_t)h * (2 * SL - 1) * DH;

        // ---- Q fragments: direct strided gather (coalesced across lanes), reg split ----
        bf16x8 qfh[4], qfl[4];
#pragma unroll
        for (int ds = 0; ds < 4; ++ds) {
            const float* qp = qbase + (size_t)(16 * ds + 8 * hi) * SL + (l0 + lo);
            f32x4 xa, xb;
#pragma unroll
            for (int i = 0; i < 4; ++i) { xa[i] = qp[(size_t)i * SL]; xb[i] = qp[(size_t)(4 + i) * SL]; }
            split8(xa, xb, qfh[ds], qfl[ds]);
        }

        // ---- initial E fragments (rows rb0+lo), hi-only ----
        const int rb0 = mq * 128 - l0 + 480;          // >= 0 always
        bf16x8 eah[4];
        {
            const float* e0p = ebase + (size_t)(rb0 + lo) * DH;
#pragma unroll
            for (int ds = 0; ds < 4; ++ds) {
                const int off = 16 * ds + 8 * hi;
                cvt8(*(const f32x4*)(e0p + off), *(const f32x4*)(e0p + off + 4), eah[ds]);
            }
        }

        float* rect = srect[wid];
        float* rrow = rect + lo * 64;
        const int sw = (lo & 7) << 2;       // XOR col-swizzle: conflict-free rect access

        f32x16 o0 = ZERO16, o1 = ZERO16;    // O^T accum: d 0-31 / 32-63, col l' = lo
        float mx = -1e30f, sum = 0.f;

        for (int step = 0; step < 4; ++step) {
            const int m0 = mq * 128 + step * 32;
            const int rb = rb0 + step * 32;

            // ---- K fragments: direct strided gather + reg hi/lo split ----
            bf16x8 kh[4], kl[4];
#pragma unroll
            for (int ds = 0; ds < 4; ++ds) {
                const float* kp = kglob + (size_t)(16 * ds + 8 * hi) * SL + (m0 + lo);
                f32x4 xa, xb;
#pragma unroll
                for (int i = 0; i < 4; ++i) { xa[i] = kp[(size_t)i * SL]; xb[i] = kp[(size_t)(4 + i) * SL]; }
                split8(xa, xb, kh[ds], kl[ds]);
            }
            // ---- E lower half (rows rb+32+lo; clamp only hits unused j=63 at last step) ----
            bf16x8 ech[4];
            {
                int r1 = rb + 32 + lo; if (r1 > 1022) r1 = 1022;
                const float* e1p = ebase + (size_t)r1 * DH;
#pragma unroll
                for (int ds = 0; ds < 4; ++ds) {
                    const int off = 16 * ds + 8 * hi;
                    cvt8(*(const f32x4*)(e1p + off), *(const f32x4*)(e1p + off + 4), ech[ds]);
                }
            }
            // ---- V fragments hi/lo (native [d][m] fp32 rows) ----
            const float* v0p = vflat + (size_t)lo * SL + m0 + 8 * hi;
            const float* v1p = vflat + (size_t)(32 + lo) * SL + m0 + 8 * hi;
            bf16x8 v00h, v00l, v01h, v01l, v10h, v10l, v11h, v11l;
            split8(*(const f32x4*)v0p,        *(const f32x4*)(v0p + 4),  v00h, v00l);
            split8(*(const f32x4*)(v0p + 16), *(const f32x4*)(v0p + 20), v01h, v01l);
            split8(*(const f32x4*)v1p,        *(const f32x4*)(v1p + 4),  v10h, v10l);
            split8(*(const f32x4*)(v1p + 16), *(const f32x4*)(v1p + 20), v11h, v11l);

            // ---- MFMA block: S^T (3-term split) + rel rect ----
            f32x16 ra = ZERO16, rc = ZERO16, sacc = ZERO16;
            __builtin_amdgcn_s_setprio(1);
#pragma unroll
            for (int ds = 0; ds < 4; ++ds) {
                sacc = MFMA(kh[ds], qfh[ds], sacc);
                sacc = MFMA(kh[ds], qfl[ds], sacc);
                sacc = MFMA(kl[ds], qfh[ds], sacc);
                ra   = MFMA(eah[ds], qfh[ds], ra);   // rel rows j = 0..31
                rc   = MFMA(ech[ds], qfh[ds], rc);   // rel rows j = 32..63
            }
            __builtin_amdgcn_s_setprio(0);

            // rect -> LDS [l'][j^sw] (8 x b128, conflict-free), sheared gather back (own row)
#pragma unroll
            for (int g = 0; g < 4; ++g) {
                const int j0 = 8 * g + 4 * hi;
                f32x4 w0 = { ra[4 * g], ra[4 * g + 1], ra[4 * g + 2], ra[4 * g + 3] };
                f32x4 w1 = { rc[4 * g], rc[4 * g + 1], rc[4 * g + 2], rc[4 * g + 3] };
                *(f32x4*)(rrow + (j0 ^ sw))        = w0;
                *(f32x4*)(rrow + ((j0 + 32) ^ sw)) = w1;
            }
            float s[16];
#pragma unroll
            for (int r = 0; r < 16; ++r) {
                const int mp = (r & 3) + 8 * (r >> 2) + 4 * hi;   // m' of this reg
                s[r] = sacc[r] + rrow[(mp + 31 - lo) ^ sw];       // + rel^T[j=m'+31-l'][l']
            }

            // ---- online softmax (per-lane col l'; hi-pair merged via shfl_xor 32) ----
            float tmx = s[0];
#pragma unroll
            for (int r = 1; r < 16; ++r) tmx = fmaxf(tmx, s[r]);
            tmx = fmaxf(tmx, __shfl_xor(tmx, 32, 64));
            const float nmx = fmaxf(mx, tmx);
            if (__any(nmx > mx)) {
                const float sc = __expf(mx - nmx);
#pragma unroll
                for (int r = 0; r < 16; ++r) { o0[r] *= sc; o1[r] *= sc; }
                sum *= sc;
                mx = nmx;
            }
            u32 pk[8], xk[8];
            float ps = 0.f;
#pragma unroll
            for (int q2 = 0; q2 < 8; ++q2) {
                union { __hip_bfloat162 b2; u32 u; } cv;
                cv.b2 = __float22bfloat162_rn(make_float2(__expf(s[2 * q2] - mx),
                                                          __expf(s[2 * q2 + 1] - mx)));
                pk[q2] = cv.u;
                float2 g2 = __bfloat1622float2(cv.b2);   // sum the *rounded* P for consistency
                ps += g2.x + g2.y;
            }
            sum += ps;
#pragma unroll
            for (int q2 = 0; q2 < 8; ++q2) xk[q2] = (u32)__shfl_xor((int)pk[q2], 32, 64);

            // P^T B-fragments (k = m within 16-slice; swap middle quads with hi-partner)
            union { u32 u[4]; bf16x8 v; } pf0, pf1;
            if (hi == 0) {
                pf0.u[0] = pk[0]; pf0.u[1] = pk[1]; pf0.u[2] = xk[0]; pf0.u[3] = xk[1];
                pf1.u[0] = pk[4]; pf1.u[1] = pk[5]; pf1.u[2] = xk[4]; pf1.u[3] = xk[5];
            } else {
                pf0.u[0] = xk[2]; pf0.u[1] = xk[3]; pf0.u[2] = pk[2]; pf0.u[3] = pk[3];
                pf1.u[0] = xk[6]; pf1.u[1] = xk[7]; pf1.u[2] = pk[6]; pf1.u[3] = pk[7];
            }
            __builtin_amdgcn_s_setprio(1);
            o0 = MFMA(v00h, pf0.v, o0);
            o0 = MFMA(v00l, pf0.v, o0);
            o0 = MFMA(v01h, pf1.v, o0);
            o0 = MFMA(v01l, pf1.v, o0);
            o1 = MFMA(v10h, pf0.v, o1);
            o1 = MFMA(v10l, pf0.v, o1);
            o1 = MFMA(v11h, pf1.v, o1);
            o1 = MFMA(v11l, pf1.v, o1);
            __builtin_amdgcn_s_setprio(0);

            // ---- E register reuse: this step's lower rows are next step's upper rows ----
#pragma unroll
            for (int ds = 0; ds < 4; ++ds) eah[ds] = ech[ds];
        }

        // merge hi-pair partial sums (mx already identical across the pair)
        sum += __shfl_xor(sum, 32, 64);

        // ---- 4-way flash merge: waves 1-3 publish, wave 0 combines & stores ----
        if (wid > 0) {
            if (hi == 0) { sstat[wid][0][lo] = mx; sstat[wid][1][lo] = sum; }
            float* ob = rect;   // reuse own rect region as [d][l'] (stride 32, conflict-free)
#pragma unroll
            for (int r = 0; r < 16; ++r) {
                const int d0 = (r & 3) + 8 * (r >> 2) + 4 * hi;
                ob[d0 * 32 + lo]        = o0[r];
                ob[(32 + d0) * 32 + lo] = o1[r];
            }
        }
        __syncthreads();
        if (wid == 0) {
            const float m1 = sstat[1][0][lo], s1 = sstat[1][1][lo];
            const float m2 = sstat[2][0][lo], s2 = sstat[2][1][lo];
            const float m3 = sstat[3][0][lo], s3 = sstat[3][1][lo];
            const float nm = fmaxf(fmaxf(mx, m1), fmaxf(m2, m3));
            const float a0 = __expf(mx - nm);
            const float a1 = __expf(m1 - nm);
            const float a2 = __expf(m2 - nm);
            const float a3 = __expf(m3 - nm);
            const float inv = 1.f / (a0 * sum + a1 * s1 + a2 * s2 + a3 * s3);
            const float* ob1 = srect[1];
            const float* ob2 = srect[2];
            const float* ob3 = srect[3];
            float* orow = out + ((size_t)bh * SL + l0 + lo) * DH;
#pragma unroll
            for (int r = 0; r < 16; r += 2) {
                const int d0 = (r & 3) + 8 * (r >> 2) + 4 * hi;   // even; (r,r+1)->(d0,d0+1)
                float2 w0 = make_float2(
                    (a0 * o0[r]     + a1 * ob1[d0 * 32 + lo] + a2 * ob2[d0 * 32 + lo] + a3 * ob3[d0 * 32 + lo]) * inv,
                    (a0 * o0[r + 1] + a1 * ob1[(d0 + 1) * 32 + lo] + a2 * ob2[(d0 + 1) * 32 + lo] + a3 * ob3[(d0 + 1) * 32 + lo]) * inv);
                *(float2*)(orow + d0) = w0;
                float2 w1 = make_float2(
                    (a0 * o1[r]     + a1 * ob1[(32 + d0) * 32 + lo] + a2 * ob2[(32 + d0) * 32 + lo] + a3 * ob3[(32 + d0) * 32 + lo]) * inv,
                    (a0 * o1[r + 1] + a1 * ob1[(32 + d0 + 1) * 32 + lo] + a2 * ob2[(32 + d0 + 1) * 32 + lo] + a3 * ob3[(32 + d0 + 1) * 32 + lo]) * inv);
                *(float2*)(orow + 32 + d0) = w1;
            }
        }
    } else {
        // ================= scalar bf16 fallback (data is bf16) =================
        const __hip_bfloat16* qkv   = (const __hip_bfloat16*)qkv_v;
        const __hip_bfloat16* k_emb = (const __hip_bfloat16*)k_emb_v;
        __hip_bfloat16* out         = (__hip_bfloat16*)out_v;

        for (int it = 0; it < 32; ++it) {
            const int row = bid * 32 + it;
            const int l   = row & (SL - 1);
            const int bh  = row >> 9;
            const int h   = bh & (NH - 1);
            const long base = (long)bh * (3 * DH) * SL;

            __syncthreads();
            if (t < DH) s_q[t] = ldv(&qkv[base + (long)t * SL + l]);
            __syncthreads();

            const __hip_bfloat16* kp = qkv + base + (long)DH * SL;
            const __hip_bfloat16* ke = k_emb + (long)h * (2 * SL - 1) * DH;
            float lg[2];
#pragma unroll
            for (int i = 0; i < 2; ++i) {
                const int m = t + i * 256;
                float acc = 0.f;
#pragma unroll 8
                for (int d = 0; d < DH; ++d)
                    acc += s_q[d] * ldv(&kp[(long)d * SL + m]);
                const int r = m - l + (SL - 1);
                const __hip_bfloat16* kr = ke + (long)r * DH;
                float acc2 = 0.f;
#pragma unroll 8
                for (int d = 0; d < DH; ++d)
                    acc2 += s_q[d] * ldv(&kr[d]);
                lg[i] = acc + acc2;
            }

            float mxv = fmaxf(lg[0], lg[1]);
            for (int off = 32; off > 0; off >>= 1)
                mxv = fmaxf(mxv, __shfl_down(mxv, off, 64));
            if ((t & 63) == 0) s_red[t >> 6] = mxv;
            __syncthreads();
            if (t == 0)
                s_red[8] = fmaxf(fmaxf(s_red[0], s_red[1]), fmaxf(s_red[2], s_red[3]));
            __syncthreads();
            mxv = s_red[8];

            const float e0 = expf(lg[0] - mxv);
            const float e1 = expf(lg[1] - mxv);
            s_w[t] = e0;
            s_w[t + 256] = e1;
            float sm = e0 + e1;
            for (int off = 32; off > 0; off >>= 1)
                sm += __shfl_down(sm, off, 64);
            if ((t & 63) == 0) s_red[16 + (t >> 6)] = sm;
            __syncthreads();
            const float inv = 1.0f / (s_red[16] + s_red[17] + s_red[18] + s_red[19]);

            const __hip_bfloat16* vp = qkv + base + (long)(2 * DH) * SL;
            const int g  = t >> 6;
            const int dd = t & 63;
            const __hip_bfloat16* vrow = vp + (long)dd * SL + g * 128;
            const float* wrow = s_w + g * 128;
            float acc = 0.f;
#pragma unroll 8
            for (int m = 0; m < 128; ++m)
                acc += wrow[m] * ldv(&vrow[m]);
            s_part[t] = acc;
            __syncthreads();
            if (t < 64) {
                float o = (s_part[t] + s_part[t + 64] + s_part[t + 128] + s_part[t + 192]) * inv;
                stv(&out[((long)bh * SL + l) * DH + t], o);
            }
        }
    }
}

extern "C" void kernel_launch(void* const* d_in, const int* in_sizes, int n_in,
                              void* d_out, int out_size, void* d_ws, size_t ws_size,
                              hipStream_t stream) {
    (void)in_sizes; (void)n_in; (void)out_size; (void)d_ws; (void)ws_size;
    attn_fused<<<1024, 256, 0, stream>>>(d_in[0], d_in[1], d_out);
}